// Round 17
// baseline (745.361 us; speedup 1.0000x reference)
//
#include <hip/hip_runtime.h>
#include <math.h>

#define TB 256

typedef short bf16x8 __attribute__((ext_vector_type(8)));
typedef short s16x4 __attribute__((ext_vector_type(4)));
typedef float f32x4 __attribute__((ext_vector_type(4)));
typedef unsigned short u16;

__device__ __forceinline__ float b2f(u16 u){
  union{unsigned i; float f;} v; v.i=((unsigned)u)<<16; return v.f;
}
__device__ __forceinline__ u16 f2b(float f){
  union{float ff; unsigned i;} v; v.ff=f;
  return (u16)((v.i + 0x7FFFu + ((v.i>>16)&1u))>>16);
}

// exact-GELU via Abramowitz-Stegun 7.1.26 erf (|err|<1.5e-7), no libcall
__device__ __forceinline__ float gelu(float x){
  float z = fabsf(x)*0.70710678118654752f;
  float t = 1.0f/fmaf(0.3275911f, z, 1.0f);
  float p = t*fmaf(t, fmaf(t, fmaf(t, fmaf(t, 1.061405429f, -1.453152027f), 1.421413741f), -0.284496736f), 0.254829592f);
  float erfz = fmaf(-p, __expf(-z*z), 1.0f);
  float s = (x >= 0.f) ? erfz : -erfz;
  return 0.5f*x*(1.0f + s);
}

// ---------------- fused prep: weight bf16 conversion + biasT [h][k][q] 64x64 ----------------
__global__ void k_prep(const float* __restrict__ qkv_w, const float* __restrict__ proj_w,
                       const float* __restrict__ w1, const float* __restrict__ w2,
                       const float* __restrict__ btab,
                       u16* __restrict__ wq, u16* __restrict__ wp,
                       u16* __restrict__ w1b, u16* __restrict__ w2b,
                       float* __restrict__ biasT){
  int i = blockIdx.x*TB + threadIdx.x;
  if(i < 196608){ wq[i] = f2b(qkv_w[i]); return; }
  i -= 196608;
  if(i < 65536){ wp[i] = f2b(proj_w[i]); return; }
  i -= 65536;
  if(i < 262144){ w1b[i] = f2b(w1[i]); return; }
  i -= 262144;
  if(i < 262144){ w2b[i] = f2b(w2[i]); return; }
  i -= 262144;
  if(i < 32768){
    int h = i>>12, kq = i&4095, k = kq>>6, q = kq&63;
    float v = 0.f;
    if(k<49 && q<49){
      int qi=q/7, qj=q-qi*7, ki=k/7, kj=k-ki*7;
      v = btab[((qi-ki+6)*13 + (qj-kj+6))*8 + h];
    }
    biasT[i] = v;
  }
}

// ---------------- window-reverse transpose: x2lin bf16[2048][49][256] -> out f32[B,C,H,W] ----------------
__global__ __launch_bounds__(256) void k_post(const u16* __restrict__ x2lin, float* __restrict__ out){
  __shared__ u16 tile[12544];            // [cc 32][ww 8][r 49]
  const int bid = blockIdx.x;
  const int bb = bid>>6, wh=(bid>>3)&7, chunk=bid&7;
  const int wb = bb*64 + wh*8;
  for(int e=threadIdx.x; e<12544; e+=256){
    int ww = e/1568, rem = e - ww*1568, r = rem>>5, cc = rem&31;
    tile[cc*392 + ww*49 + r] = x2lin[(size_t)(wb+ww)*12544 + r*256 + chunk*32 + cc];
  }
  __syncthreads();
  for(int idx=threadIdx.x; idx<12544; idx+=256){
    int c = idx/392, rem = idx - c*392, ii = rem/56, w = rem - ii*56;
    int ww = w/7, j = w - ww*7;
    out[((size_t)(bb*256 + chunk*32 + c))*3136 + (size_t)(wh*7+ii)*56 + w]
        = b2f(tile[c*392 + ww*49 + ii*7 + j]);
  }
}

// ---------------- fully fused transformer block, 1 window / block ----------------
#define QB_OFF  32768
#define KB_OFF  65536
#define VT_OFF  98304
#define XS_OFF  65536
#define BLK_LDS 131072

__global__ __launch_bounds__(1024,2) void k_block(
    const float* __restrict__ x,
    const u16* __restrict__ wqkv,  const float* __restrict__ bqkv,
    const u16* __restrict__ wproj, const float* __restrict__ bproj,
    const float* __restrict__ biasT,
    const float* __restrict__ g1, const float* __restrict__ bt1,
    const u16* __restrict__ w1, const float* __restrict__ b1v,
    const u16* __restrict__ w2, const float* __restrict__ b2v,
    const float* __restrict__ g2, const float* __restrict__ bt2,
    u16* __restrict__ x2lin)
{
  extern __shared__ char lds[];
  const int tid = threadIdx.x;
  const int wv = tid >> 6, l = tid & 63;
  const int lr = l & 15, lg = l >> 4;
  const unsigned swzA = ((unsigned)(lr & 7)) << 4;
  const unsigned swzR = ((unsigned)((lr>>2) & 3)) << 4;
  const int win = ((blockIdx.x & 7) << 8) | (blockIdx.x >> 3);
  const int bb = win >> 6, wh = (win >> 3) & 7, ww = win & 7;
  const float* xwin = x + (size_t)bb*802816 + (size_t)wh*392 + ww*7;

  // ---- phase 0a: coalesced stage of x window -> xs f32[256][53] ----
  float* xs = (float*)(lds + XS_OFF);
  {
    const int j = tid & 7, rbase = tid >> 3;
    #pragma unroll
    for(int it=0; it<14; ++it){
      int run = it*128 + rbase;
      int c = run/7, ii = run - (run/7)*7;
      if(j<7) xs[c*53 + ii*7 + j] = xwin[(size_t)c*3136 + ii*56 + j];
    }
  }
  __syncthreads();

  // ---- phase 0b: LN1 from xs -> h_s bf16 swz; zero h_s pad rows ----
  {
    float gg[4], bgm[4];
    #pragma unroll
    for(int k2=0;k2<4;++k2){ gg[k2]=g1[l+64*k2]; bgm[k2]=bt1[l+64*k2]; }
    #pragma unroll
    for(int s=0;s<4;++s){
      int n = wv + s*16;
      if(n<49){
        float xv[4];
        #pragma unroll
        for(int k2=0;k2<4;++k2) xv[k2] = xs[(l+64*k2)*53 + n];
        float sm=0.f, sq=0.f;
        #pragma unroll
        for(int k2=0;k2<4;++k2){ sm+=xv[k2]; sq+=xv[k2]*xv[k2]; }
        #pragma unroll
        for(int off=32;off>=1;off>>=1){ sm+=__shfl_xor(sm,off); sq+=__shfl_xor(sq,off); }
        float mu=sm*(1.f/256.f), var=sq*(1.f/256.f)-mu*mu;
        float rs=rsqrtf(var+1e-5f);
        #pragma unroll
        for(int k2=0;k2<4;++k2){
          int c=l+64*k2;
          unsigned off2 = (((unsigned)n)*512u + ((unsigned)c)*2u) ^ (((unsigned)(n&7))<<4);
          *(u16*)(lds + off2) = f2b((xv[k2]-mu)*rs*gg[k2]+bgm[k2]);
        }
      }
    }
  }
  for(int m=tid; m<3840; m+=1024) *(u16*)(lds + 49*512 + m*2) = 0;
  __syncthreads();          // xs dead

  // ---- Vt pad zeroing (r>=49 only), disjoint from phase-1 writes ----
  for(int m=tid; m<3840; m+=1024){
    int hd = m/480, rm = m - hd*480;
    int d = rm/15, r = 49 + (rm - (rm/15)*15);
    *(u16*)(lds + ((unsigned)(VT_OFF + hd*4096 + d*128 + r*2) ^ ((((unsigned)d)&7u)<<4))) = 0;
  }

  // ---- phase 1: QKV GEMM (transposed D[c][r]); quarter fragment loads, acc[4] ILP ----
  for(int ct=wv; ct<48; ct+=16){
    const u16* wrow = wqkv + ((size_t)(ct*16+lr))*256 + lg*8;
    f32x4 acc[4];
    #pragma unroll
    for(int rt=0;rt<4;++rt) acc[rt]=(f32x4){0.f,0.f,0.f,0.f};
    #pragma unroll
    for(int kq=0; kq<4; ++kq){
      bf16x8 bfr[2];
      #pragma unroll
      for(int k=0;k<2;++k) bfr[k] = *(const bf16x8*)(wrow + kq*64 + k*32);
      #pragma unroll
      for(int rt=0; rt<4; ++rt){
        #pragma unroll
        for(int k=0;k<2;++k){
          bf16x8 afr = *(const bf16x8*)(lds + ((((unsigned)(rt*16+lr))*512u + (unsigned)((kq*2+k)*64+lg*16)) ^ swzA));
          acc[rt] = __builtin_amdgcn_mfma_f32_16x16x32_bf16(bfr[k], afr, acc[rt], 0,0,0);
        }
      }
    }
    f32x4 b4 = *(const f32x4*)(bqkv + ct*16 + lg*4);
    const int s3 = ct>>4, hd = (ct>>1)&7, db = (ct&1)*16 + lg*4;
    #pragma unroll
    for(int rt=0; rt<4; ++rt){
      const int r = rt*16 + lr;
      if(r<49){
        if(s3==0){
          s16x4 pk;
          #pragma unroll
          for(int i=0;i<4;++i) pk[i] = (short)f2b((acc[rt][i]+b4[i])*0.35355339059327373f);
          *(s16x4*)(lds + ((unsigned)(QB_OFF + hd*4096 + r*64 + db*2) ^ swzR)) = pk;
        } else if(s3==1){
          s16x4 pk;
          #pragma unroll
          for(int i=0;i<4;++i) pk[i] = (short)f2b(acc[rt][i]+b4[i]);
          *(s16x4*)(lds + ((unsigned)(KB_OFF + hd*4096 + r*64 + db*2) ^ swzR)) = pk;
        } else {
          #pragma unroll
          for(int i=0;i<4;++i)
            *(u16*)(lds + ((unsigned)(VT_OFF + hd*4096 + (db+i)*128 + r*2) ^ ((((unsigned)(db+i))&7u)<<4))) = f2b(acc[rt][i]+b4[i]);
        }
      }
    }
  }
  __syncthreads();

  // ---- phase 2: attention; 2 waves per head, qt halves sequential ----
  {
    const int h = wv & 7, half = wv >> 3;
    s16x4 pkk[2][4];
    #pragma unroll
    for(int j=0;j<2;++j){
      const int qt = half*2 + j;
      bf16x8 qf = *(const bf16x8*)(lds + ((unsigned)(QB_OFF + h*4096 + (qt*16+lr)*64 + lg*16) ^ swzR));
      f32x4 st[4];
      #pragma unroll
      for(int kt=0;kt<4;++kt){
        bf16x8 kfk = *(const bf16x8*)(lds + ((unsigned)(KB_OFF + h*4096 + (kt*16+lr)*64 + lg*16) ^ swzR));
        f32x4 bini;
        #pragma unroll
        for(int i=0;i<4;++i) bini[i] = biasT[h*4096 + (kt*16+lg*4+i)*64 + qt*16+lr];
        st[kt] = __builtin_amdgcn_mfma_f32_16x16x32_bf16(kfk, qf, bini, 0,0,0);
      }
      #pragma unroll
      for(int i=0;i<4;++i)
        if(!(lg==0 && i==0)) st[3][i] = -1e30f;   // only k=48 valid in kt=3

      float mx = -1e30f;
      #pragma unroll
      for(int kt=0;kt<4;++kt)
        #pragma unroll
        for(int i=0;i<4;++i) mx = fmaxf(mx, st[kt][i]);
      mx = fmaxf(mx, __shfl_xor(mx,16));
      mx = fmaxf(mx, __shfl_xor(mx,32));
      float su = 0.f;
      #pragma unroll
      for(int kt=0;kt<4;++kt)
        #pragma unroll
        for(int i=0;i<4;++i){ float p = __expf(st[kt][i]-mx); st[kt][i]=p; su+=p; }
      su += __shfl_xor(su,16);
      su += __shfl_xor(su,32);
      float inv = 1.f/su;
      #pragma unroll
      for(int kt=0;kt<4;++kt)
        #pragma unroll
        for(int i=0;i<4;++i) pkk[j][kt][i] = (short)f2b(st[kt][i]*inv);
    }
    __syncthreads();       // Qbuf/Kbuf reads done -> P may overwrite [0,64K)

    char* Pb = lds + h*8192;
    #pragma unroll
    for(int j=0;j<2;++j){
      const unsigned rq = (unsigned)((half*2+j)*16 + lr);
      #pragma unroll
      for(int kt=0;kt<4;++kt)
        *(s16x4*)(Pb + ((rq*128u + (unsigned)(kt*32+lg*8)) ^ swzA)) = pkk[j][kt];
    }
    #pragma unroll
    for(int j=0;j<2;++j){
      const int qt = half*2 + j;
      const unsigned rq = (unsigned)(qt*16 + lr);
      bf16x8 pf0 = *(const bf16x8*)(Pb + ((rq*128u + (unsigned)(lg*16)) ^ swzA));
      bf16x8 pf1 = *(const bf16x8*)(Pb + ((rq*128u + (unsigned)(64+lg*16)) ^ swzA));
      #pragma unroll
      for(int dt=0;dt<2;++dt){
        bf16x8 vf0 = *(const bf16x8*)(lds + ((unsigned)(VT_OFF + h*4096 + (dt*16+lr)*128 + lg*16) ^ swzA));
        bf16x8 vf1 = *(const bf16x8*)(lds + ((unsigned)(VT_OFF + h*4096 + (dt*16+lr)*128 + 64+lg*16) ^ swzA));
        f32x4 o = {0.f,0.f,0.f,0.f};
        o = __builtin_amdgcn_mfma_f32_16x16x32_bf16(pf0, vf0, o, 0,0,0);
        o = __builtin_amdgcn_mfma_f32_16x16x32_bf16(pf1, vf1, o, 0,0,0);
        #pragma unroll
        for(int i=0;i<4;++i)
          *(u16*)(lds + ((unsigned)(KB_OFF + h*4096 + (qt*16+lg*4+i)*64 + (dt*16+lr)*2) ^ (((unsigned)lg)<<4))) = f2b(o[i]);
      }
    }
  }
  __syncthreads();         // O ready; P dead

  // ---- phase 3: proj GEMM + residual(global re-read, L2-hot); quarter fragments ----
  {
    const int c = wv*16 + lr;
    const u16* wrow = wproj + (size_t)c*256 + lg*8;
    const float pbP = bproj[c];
    f32x4 acc[4];
    #pragma unroll
    for(int mt=0;mt<4;++mt) acc[mt]=(f32x4){0.f,0.f,0.f,0.f};
    #pragma unroll
    for(int kq=0; kq<4; ++kq){
      bf16x8 bfrP[2];
      #pragma unroll
      for(int k=0;k<2;++k) bfrP[k] = *(const bf16x8*)(wrow + kq*64 + k*32);
      #pragma unroll
      for(int mt=0; mt<4; ++mt){
        #pragma unroll
        for(int k=0;k<2;++k){
          bf16x8 afr = *(const bf16x8*)(lds + ((unsigned)(KB_OFF + (kq*2+k)*4096 + (mt*16+lr)*64 + lg*16) ^ swzR));
          acc[mt] = __builtin_amdgcn_mfma_f32_16x16x32_bf16(afr, bfrP[k], acc[mt], 0,0,0);
        }
      }
    }
    #pragma unroll
    for(int mt=0; mt<4; ++mt){
      #pragma unroll
      for(int i=0;i<4;++i){
        int r = mt*16 + lg*4 + i;
        if(r<49){
          int ii=r/7, jj=r-ii*7;
          float val = acc[mt][i] + pbP + xwin[(size_t)c*3136 + ii*56 + jj];
          *(u16*)(lds + ((((unsigned)r)*512u + ((unsigned)c)*2u) ^ (((unsigned)(r&7))<<4))) = f2b(val);
        }
      }
    }
  }
  for(int m=tid; m<3840; m+=1024){   // zero xt pad rows (swizzled)
    int r = 49 + (m>>8), c = m & 255;
    *(u16*)(lds + ((((unsigned)r)*512u + ((unsigned)c)*2u) ^ (((unsigned)(r&7))<<4))) = 0;
  }
  __syncthreads();

  // ---- phase 4: LN2 (xt bf16) -> h2s at [32,64K) ----
  {
    float gg[4], bb2[4];
    #pragma unroll
    for(int k2=0;k2<4;++k2){ gg[k2]=g2[l+64*k2]; bb2[k2]=bt2[l+64*k2]; }
    #pragma unroll
    for(int rr=0; rr<4; ++rr){
      int r = wv*4 + rr;
      float v[4];
      #pragma unroll
      for(int k2=0;k2<4;++k2)
        v[k2] = b2f(*(const u16*)(lds + ((((unsigned)r)*512u + ((unsigned)(l+64*k2))*2u) ^ (((unsigned)(r&7))<<4))));
      float sm=v[0]+v[1]+v[2]+v[3];
      float sq=v[0]*v[0]+v[1]*v[1]+v[2]*v[2]+v[3]*v[3];
      #pragma unroll
      for(int off=32;off>=1;off>>=1){ sm+=__shfl_xor(sm,off); sq+=__shfl_xor(sq,off); }
      float mu=sm*(1.f/256.f), var=sq*(1.f/256.f)-mu*mu, rs=rsqrtf(var+1e-5f);
      #pragma unroll
      for(int k2=0;k2<4;++k2){
        int c=l+64*k2;
        unsigned off2 = 32768u + ((((unsigned)r)*512u + ((unsigned)c)*2u) ^ (((unsigned)(r&7))<<4));
        *(u16*)(lds + off2) = f2b((v[k2]-mu)*rs*gg[k2]+bb2[k2]);
      }
    }
  }
  __syncthreads();

  // ---- phase 5: MLP with double-buffered hid; quarter fragments, acc[4] ILP ----
  const int hcol = wv*16 + lr;
  f32x4 acc2[4];
  #pragma unroll
  for(int mt=0;mt<4;++mt) acc2[mt]=(f32x4){0.f,0.f,0.f,0.f};

  // G1(0) -> hid0
  {
    const u16* wrow = w1 + (size_t)hcol*256 + lg*8;
    const float bias1 = b1v[hcol];
    f32x4 acc[4];
    #pragma unroll
    for(int mt=0;mt<4;++mt) acc[mt]=(f32x4){0.f,0.f,0.f,0.f};
    #pragma unroll
    for(int kq=0; kq<4; ++kq){
      bf16x8 bfr1[2];
      #pragma unroll
      for(int k=0;k<2;++k) bfr1[k] = *(const bf16x8*)(wrow + kq*64 + k*32);
      #pragma unroll
      for(int mt=0; mt<4; ++mt){
        #pragma unroll
        for(int k=0;k<2;++k){
          bf16x8 afr = *(const bf16x8*)(lds + 32768u + ((((unsigned)(mt*16+lr))*512u + (unsigned)((kq*2+k)*64+lg*16)) ^ swzA));
          acc[mt] = __builtin_amdgcn_mfma_f32_16x16x32_bf16(afr, bfr1[k], acc[mt], 0,0,0);
        }
      }
    }
    #pragma unroll
    for(int mt=0; mt<4; ++mt)
      #pragma unroll
      for(int i2=0;i2<4;++i2){
        int r = mt*16 + lg*4 + i2;
        *(u16*)(lds + 98304u + ((((unsigned)r)*512u + ((unsigned)hcol)*2u) ^ (((unsigned)(r&7))<<4))) = f2b(gelu(acc[mt][i2]+bias1));
      }
  }
  __syncthreads();

  for(int kc=0; kc<4; ++kc){
    // G1(kc+1) -> other hid buffer
    if(kc<3){
      const int gcol = (kc+1)*256 + hcol;
      const u16* wrow = w1 + (size_t)gcol*256 + lg*8;
      const float biasN = b1v[gcol];
      const unsigned dst = ((kc+1)&1) ? 65536u : 98304u;
      f32x4 acc[4];
      #pragma unroll
      for(int mt=0;mt<4;++mt) acc[mt]=(f32x4){0.f,0.f,0.f,0.f};
      #pragma unroll
      for(int kq=0; kq<4; ++kq){
        bf16x8 bfrN[2];
        #pragma unroll
        for(int k=0;k<2;++k) bfrN[k] = *(const bf16x8*)(wrow + kq*64 + k*32);
        #pragma unroll
        for(int mt=0; mt<4; ++mt){
          #pragma unroll
          for(int k=0;k<2;++k){
            bf16x8 afr = *(const bf16x8*)(lds + 32768u + ((((unsigned)(mt*16+lr))*512u + (unsigned)((kq*2+k)*64+lg*16)) ^ swzA));
            acc[mt] = __builtin_amdgcn_mfma_f32_16x16x32_bf16(afr, bfrN[k], acc[mt], 0,0,0);
          }
        }
      }
      #pragma unroll
      for(int mt=0; mt<4; ++mt)
        #pragma unroll
        for(int i2=0;i2<4;++i2){
          int r = mt*16 + lg*4 + i2;
          *(u16*)(lds + dst + ((((unsigned)r)*512u + ((unsigned)hcol)*2u) ^ (((unsigned)(r&7))<<4))) = f2b(gelu(acc[mt][i2]+biasN));
        }
    }
    // G2(kc) reads current hid buffer
    {
      const u16* wrow = w2 + (size_t)hcol*1024 + kc*256 + lg*8;
      const unsigned src = (kc&1) ? 65536u : 98304u;
      __builtin_amdgcn_s_setprio(1);
      #pragma unroll
      for(int kq=0; kq<4; ++kq){
        bf16x8 bfr2[2];
        #pragma unroll
        for(int k=0;k<2;++k) bfr2[k] = *(const bf16x8*)(wrow + kq*64 + k*32);
        #pragma unroll
        for(int mt=0; mt<4; ++mt){
          #pragma unroll
          for(int k=0;k<2;++k){
            bf16x8 afr = *(const bf16x8*)(lds + src + ((((unsigned)(mt*16+lr))*512u + (unsigned)((kq*2+k)*64+lg*16)) ^ swzA));
            acc2[mt] = __builtin_amdgcn_mfma_f32_16x16x32_bf16(afr, bfr2[k], acc2[mt], 0,0,0);
          }
        }
      }
      __builtin_amdgcn_s_setprio(0);
    }
    __syncthreads();
  }

  // ---- epilogue: final = mlp + b2 + x2(bf16), f32 into [32,96K) ----
  {
    const int c = hcol;
    const float biasc = b2v[c];
    #pragma unroll
    for(int mt=0; mt<4; ++mt){
      #pragma unroll
      for(int i2=0;i2<4;++i2){
        int r = mt*16 + lg*4 + i2;
        float resid = b2f(*(const u16*)(lds + ((((unsigned)r)*512u + ((unsigned)c)*2u) ^ (((unsigned)(r&7))<<4))));
        float val = acc2[mt][i2] + biasc + resid;
        *(float*)(lds + 32768u + ((((unsigned)r)*1024u + ((unsigned)c)*4u) ^ ((((unsigned)(r>>2))&3u)<<6))) = val;
      }
    }
  }
  __syncthreads();

  // ---- writeout: linear bf16 x2lin[win][49][256], fully coalesced ----
  for(int u=tid; u<12544; u+=1024){
    int r = u>>8, c = u&255;
    float v = *(const float*)(lds + 32768u + ((((unsigned)r)*1024u + ((unsigned)c)*4u) ^ ((((unsigned)(r>>2))&3u)<<6)));
    x2lin[(size_t)win*12544 + u] = f2b(v);
  }
}

extern "C" void kernel_launch(void* const* d_in, const int* in_sizes, int n_in,
                              void* d_out, int out_size, void* d_ws, size_t ws_size,
                              hipStream_t stream) {
  const float* x      = (const float*)d_in[0];
  const float* qkv_w  = (const float*)d_in[1];
  const float* qkv_b  = (const float*)d_in[2];
  const float* proj_w = (const float*)d_in[3];
  const float* proj_b = (const float*)d_in[4];
  const float* btab   = (const float*)d_in[5];
  const float* ln1g   = (const float*)d_in[6];
  const float* ln1b   = (const float*)d_in[7];
  const float* ln2g   = (const float*)d_in[8];
  const float* ln2b   = (const float*)d_in[9];
  const float* w1     = (const float*)d_in[10];
  const float* b1     = (const float*)d_in[11];
  const float* w2     = (const float*)d_in[12];
  const float* b2     = (const float*)d_in[13];

  char* ws = (char*)d_ws;
  float* biasT = (float*)ws;                     // 131,072 B
  u16*   wq    = (u16*)(ws + 131072);            // 393,216 B
  u16*   wp    = (u16*)(ws + 524288);            // 131,072 B
  u16*   w1b   = (u16*)(ws + 655360);            // 524,288 B
  u16*   w2b   = (u16*)(ws + 1179648);           // 524,288 B
  u16*   x2l   = (u16*)(ws + 1703936);           // 51,380,224 B -> total 53,084,160 B

  k_prep<<<3200, TB, 0, stream>>>(qkv_w, proj_w, w1, w2, btab, wq, wp, w1b, w2b, biasT);

  hipFuncSetAttribute((const void*)k_block, hipFuncAttributeMaxDynamicSharedMemorySize, BLK_LDS);
  k_block<<<2048, 1024, BLK_LDS, stream>>>(x, wq, qkv_b, wp, proj_b, biasT, ln1g, ln1b,
                                           w1b, b1, w2b, b2, ln2g, ln2b, x2l);
  k_post<<<2048, 256, 0, stream>>>(x2l, (float*)d_out);
}

// Round 18
// 714.591 us; speedup vs baseline: 1.0431x; 1.0431x over previous
//
#include <hip/hip_runtime.h>
#include <math.h>

#define TB 256

typedef short bf16x8 __attribute__((ext_vector_type(8)));
typedef short s16x4 __attribute__((ext_vector_type(4)));
typedef float f32x4 __attribute__((ext_vector_type(4)));
typedef unsigned short u16;

__device__ __forceinline__ float b2f(u16 u){
  union{unsigned i; float f;} v; v.i=((unsigned)u)<<16; return v.f;
}
__device__ __forceinline__ u16 f2b(float f){
  union{float ff; unsigned i;} v; v.ff=f;
  return (u16)((v.i + 0x7FFFu + ((v.i>>16)&1u))>>16);
}

// exact-GELU via Abramowitz-Stegun 7.1.26 erf (|err|<1.5e-7), no libcall
__device__ __forceinline__ float gelu(float x){
  float z = fabsf(x)*0.70710678118654752f;
  float t = 1.0f/fmaf(0.3275911f, z, 1.0f);
  float p = t*fmaf(t, fmaf(t, fmaf(t, fmaf(t, 1.061405429f, -1.453152027f), 1.421413741f), -0.284496736f), 0.254829592f);
  float erfz = fmaf(-p, __expf(-z*z), 1.0f);
  float s = (x >= 0.f) ? erfz : -erfz;
  return 0.5f*x*(1.0f + s);
}

// ---------------- fused prep: weight bf16 conversion + biasT [h][k][q] 64x64 ----------------
__global__ void k_prep(const float* __restrict__ qkv_w, const float* __restrict__ proj_w,
                       const float* __restrict__ w1, const float* __restrict__ w2,
                       const float* __restrict__ btab,
                       u16* __restrict__ wq, u16* __restrict__ wp,
                       u16* __restrict__ w1b, u16* __restrict__ w2b,
                       float* __restrict__ biasT){
  int i = blockIdx.x*TB + threadIdx.x;
  if(i < 196608){ wq[i] = f2b(qkv_w[i]); return; }
  i -= 196608;
  if(i < 65536){ wp[i] = f2b(proj_w[i]); return; }
  i -= 65536;
  if(i < 262144){ w1b[i] = f2b(w1[i]); return; }
  i -= 262144;
  if(i < 262144){ w2b[i] = f2b(w2[i]); return; }
  i -= 262144;
  if(i < 32768){
    int h = i>>12, kq = i&4095, k = kq>>6, q = kq&63;
    float v = 0.f;
    if(k<49 && q<49){
      int qi=q/7, qj=q-qi*7, ki=k/7, kj=k-ki*7;
      v = btab[((qi-ki+6)*13 + (qj-kj+6))*8 + h];
    }
    biasT[i] = v;
  }
}

// ---------------- window-reverse transpose: x2lin bf16[2048][49][256] -> out f32[B,C,H,W] ----------------
__global__ __launch_bounds__(256) void k_post(const u16* __restrict__ x2lin, float* __restrict__ out){
  __shared__ u16 tile[12544];            // [cc 32][ww 8][r 49]
  const int bid = blockIdx.x;
  const int bb = bid>>6, wh=(bid>>3)&7, chunk=bid&7;
  const int wb = bb*64 + wh*8;
  for(int e=threadIdx.x; e<12544; e+=256){
    int ww = e/1568, rem = e - ww*1568, r = rem>>5, cc = rem&31;
    tile[cc*392 + ww*49 + r] = x2lin[(size_t)(wb+ww)*12544 + r*256 + chunk*32 + cc];
  }
  __syncthreads();
  for(int idx=threadIdx.x; idx<12544; idx+=256){
    int c = idx/392, rem = idx - c*392, ii = rem/56, w = rem - ii*56;
    int ww = w/7, j = w - ww*7;
    out[((size_t)(bb*256 + chunk*32 + c))*3136 + (size_t)(wh*7+ii)*56 + w]
        = b2f(tile[c*392 + ww*49 + ii*7 + j]);
  }
}

// ---------------- k_attn: LN1 + QKV + attention + proj + residual -> xt linear ----------------
#define QB_OFF  32768
#define KB_OFF  65536
#define VT_OFF  98304
#define XS_OFF  65536
#define ATT_LDS 131072

__global__ __launch_bounds__(1024,4) void k_attn(
    const float* __restrict__ x,
    const u16* __restrict__ wqkv,  const float* __restrict__ bqkv,
    const u16* __restrict__ wproj, const float* __restrict__ bproj,
    const float* __restrict__ biasT,
    const float* __restrict__ g1, const float* __restrict__ bt1,
    u16* __restrict__ xtbuf)          // xt bf16 [win][49][256] (scratch in d_out)
{
  extern __shared__ char lds[];
  const int tid = threadIdx.x;
  const int wv = tid >> 6, l = tid & 63;
  const int lr = l & 15, lg = l >> 4;
  const unsigned swzA = ((unsigned)(lr & 7)) << 4;
  const unsigned swzR = ((unsigned)((lr>>2) & 3)) << 4;
  const int win = ((blockIdx.x & 7) << 8) | (blockIdx.x >> 3);
  const int bb = win >> 6, wh = (win >> 3) & 7, ww = win & 7;
  const float* xwin = x + (size_t)bb*802816 + (size_t)wh*392 + ww*7;

  // ---- phase 0a: coalesced stage of x window -> xs f32[256][53] ----
  float* xs = (float*)(lds + XS_OFF);
  {
    const int j = tid & 7, rbase = tid >> 3;
    #pragma unroll
    for(int it=0; it<14; ++it){
      int run = it*128 + rbase;
      int c = run/7, ii = run - (run/7)*7;
      if(j<7) xs[c*53 + ii*7 + j] = xwin[(size_t)c*3136 + ii*56 + j];
    }
  }
  __syncthreads();

  // ---- phase 0b: LN1 from xs -> h_s bf16 swz; zero h_s pad rows ----
  {
    float gg[4], bgm[4];
    #pragma unroll
    for(int k2=0;k2<4;++k2){ gg[k2]=g1[l+64*k2]; bgm[k2]=bt1[l+64*k2]; }
    #pragma unroll
    for(int s=0;s<4;++s){
      int n = wv + s*16;
      if(n<49){
        float xv[4];
        #pragma unroll
        for(int k2=0;k2<4;++k2) xv[k2] = xs[(l+64*k2)*53 + n];
        float sm=0.f, sq=0.f;
        #pragma unroll
        for(int k2=0;k2<4;++k2){ sm+=xv[k2]; sq+=xv[k2]*xv[k2]; }
        #pragma unroll
        for(int off=32;off>=1;off>>=1){ sm+=__shfl_xor(sm,off); sq+=__shfl_xor(sq,off); }
        float mu=sm*(1.f/256.f), var=sq*(1.f/256.f)-mu*mu;
        float rs=rsqrtf(var+1e-5f);
        #pragma unroll
        for(int k2=0;k2<4;++k2){
          int c=l+64*k2;
          unsigned off2 = (((unsigned)n)*512u + ((unsigned)c)*2u) ^ (((unsigned)(n&7))<<4);
          *(u16*)(lds + off2) = f2b((xv[k2]-mu)*rs*gg[k2]+bgm[k2]);
        }
      }
    }
  }
  for(int m=tid; m<3840; m+=1024) *(u16*)(lds + 49*512 + m*2) = 0;
  __syncthreads();          // xs dead

  // ---- Vt pad zeroing (r>=49 only), disjoint from phase-1 writes ----
  for(int m=tid; m<3840; m+=1024){
    int hd = m/480, rm = m - hd*480;
    int d = rm/15, r = 49 + (rm - (rm/15)*15);
    *(u16*)(lds + ((unsigned)(VT_OFF + hd*4096 + d*128 + r*2) ^ ((((unsigned)d)&7u)<<4))) = 0;
  }

  // ---- phase 1: QKV GEMM (transposed D[c][r]); quarter fragment loads, acc[4] ILP ----
  for(int ct=wv; ct<48; ct+=16){
    const u16* wrow = wqkv + ((size_t)(ct*16+lr))*256 + lg*8;
    f32x4 acc[4];
    #pragma unroll
    for(int rt=0;rt<4;++rt) acc[rt]=(f32x4){0.f,0.f,0.f,0.f};
    #pragma unroll
    for(int kq=0; kq<4; ++kq){
      bf16x8 bfr[2];
      #pragma unroll
      for(int k=0;k<2;++k) bfr[k] = *(const bf16x8*)(wrow + kq*64 + k*32);
      #pragma unroll
      for(int rt=0; rt<4; ++rt){
        #pragma unroll
        for(int k=0;k<2;++k){
          bf16x8 afr = *(const bf16x8*)(lds + ((((unsigned)(rt*16+lr))*512u + (unsigned)((kq*2+k)*64+lg*16)) ^ swzA));
          acc[rt] = __builtin_amdgcn_mfma_f32_16x16x32_bf16(bfr[k], afr, acc[rt], 0,0,0);
        }
      }
    }
    f32x4 b4 = *(const f32x4*)(bqkv + ct*16 + lg*4);
    const int s3 = ct>>4, hd = (ct>>1)&7, db = (ct&1)*16 + lg*4;
    #pragma unroll
    for(int rt=0; rt<4; ++rt){
      const int r = rt*16 + lr;
      if(r<49){
        if(s3==0){
          s16x4 pk;
          #pragma unroll
          for(int i=0;i<4;++i) pk[i] = (short)f2b((acc[rt][i]+b4[i])*0.35355339059327373f);
          *(s16x4*)(lds + ((unsigned)(QB_OFF + hd*4096 + r*64 + db*2) ^ swzR)) = pk;
        } else if(s3==1){
          s16x4 pk;
          #pragma unroll
          for(int i=0;i<4;++i) pk[i] = (short)f2b(acc[rt][i]+b4[i]);
          *(s16x4*)(lds + ((unsigned)(KB_OFF + hd*4096 + r*64 + db*2) ^ swzR)) = pk;
        } else {
          #pragma unroll
          for(int i=0;i<4;++i)
            *(u16*)(lds + ((unsigned)(VT_OFF + hd*4096 + (db+i)*128 + r*2) ^ ((((unsigned)(db+i))&7u)<<4))) = f2b(acc[rt][i]+b4[i]);
        }
      }
    }
  }
  __syncthreads();

  // ---- phase 2: attention; 2 waves per head, qt halves sequential ----
  {
    const int h = wv & 7, half = wv >> 3;
    s16x4 pkk[2][4];
    #pragma unroll
    for(int j=0;j<2;++j){
      const int qt = half*2 + j;
      bf16x8 qf = *(const bf16x8*)(lds + ((unsigned)(QB_OFF + h*4096 + (qt*16+lr)*64 + lg*16) ^ swzR));
      f32x4 st[4];
      #pragma unroll
      for(int kt=0;kt<4;++kt){
        bf16x8 kfk = *(const bf16x8*)(lds + ((unsigned)(KB_OFF + h*4096 + (kt*16+lr)*64 + lg*16) ^ swzR));
        f32x4 bini;
        #pragma unroll
        for(int i=0;i<4;++i) bini[i] = biasT[h*4096 + (kt*16+lg*4+i)*64 + qt*16+lr];
        st[kt] = __builtin_amdgcn_mfma_f32_16x16x32_bf16(kfk, qf, bini, 0,0,0);
      }
      #pragma unroll
      for(int i=0;i<4;++i)
        if(!(lg==0 && i==0)) st[3][i] = -1e30f;   // only k=48 valid in kt=3

      float mx = -1e30f;
      #pragma unroll
      for(int kt=0;kt<4;++kt)
        #pragma unroll
        for(int i=0;i<4;++i) mx = fmaxf(mx, st[kt][i]);
      mx = fmaxf(mx, __shfl_xor(mx,16));
      mx = fmaxf(mx, __shfl_xor(mx,32));
      float su = 0.f;
      #pragma unroll
      for(int kt=0;kt<4;++kt)
        #pragma unroll
        for(int i=0;i<4;++i){ float p = __expf(st[kt][i]-mx); st[kt][i]=p; su+=p; }
      su += __shfl_xor(su,16);
      su += __shfl_xor(su,32);
      float inv = 1.f/su;
      #pragma unroll
      for(int kt=0;kt<4;++kt)
        #pragma unroll
        for(int i=0;i<4;++i) pkk[j][kt][i] = (short)f2b(st[kt][i]*inv);
    }
    __syncthreads();       // Qbuf/Kbuf reads done -> P may overwrite [0,64K)

    char* Pb = lds + h*8192;
    #pragma unroll
    for(int j=0;j<2;++j){
      const unsigned rq = (unsigned)((half*2+j)*16 + lr);
      #pragma unroll
      for(int kt=0;kt<4;++kt)
        *(s16x4*)(Pb + ((rq*128u + (unsigned)(kt*32+lg*8)) ^ swzA)) = pkk[j][kt];
    }
    #pragma unroll
    for(int j=0;j<2;++j){
      const int qt = half*2 + j;
      const unsigned rq = (unsigned)(qt*16 + lr);
      bf16x8 pf0 = *(const bf16x8*)(Pb + ((rq*128u + (unsigned)(lg*16)) ^ swzA));
      bf16x8 pf1 = *(const bf16x8*)(Pb + ((rq*128u + (unsigned)(64+lg*16)) ^ swzA));
      #pragma unroll
      for(int dt=0;dt<2;++dt){
        bf16x8 vf0 = *(const bf16x8*)(lds + ((unsigned)(VT_OFF + h*4096 + (dt*16+lr)*128 + lg*16) ^ swzA));
        bf16x8 vf1 = *(const bf16x8*)(lds + ((unsigned)(VT_OFF + h*4096 + (dt*16+lr)*128 + 64+lg*16) ^ swzA));
        f32x4 o = {0.f,0.f,0.f,0.f};
        o = __builtin_amdgcn_mfma_f32_16x16x32_bf16(pf0, vf0, o, 0,0,0);
        o = __builtin_amdgcn_mfma_f32_16x16x32_bf16(pf1, vf1, o, 0,0,0);
        #pragma unroll
        for(int i=0;i<4;++i)
          *(u16*)(lds + ((unsigned)(KB_OFF + h*4096 + (qt*16+lg*4+i)*64 + (dt*16+lr)*2) ^ (((unsigned)lg)<<4))) = f2b(o[i]);
      }
    }
  }
  __syncthreads();         // O ready; P dead

  // ---- phase 3: proj GEMM + residual -> xt bf16 swz at [0,32K) ----
  {
    const int c = wv*16 + lr;
    const u16* wrow = wproj + (size_t)c*256 + lg*8;
    const float pbP = bproj[c];
    f32x4 acc[4];
    #pragma unroll
    for(int mt=0;mt<4;++mt) acc[mt]=(f32x4){0.f,0.f,0.f,0.f};
    #pragma unroll
    for(int kq=0; kq<4; ++kq){
      bf16x8 bfrP[2];
      #pragma unroll
      for(int k=0;k<2;++k) bfrP[k] = *(const bf16x8*)(wrow + kq*64 + k*32);
      #pragma unroll
      for(int mt=0; mt<4; ++mt){
        #pragma unroll
        for(int k=0;k<2;++k){
          bf16x8 afr = *(const bf16x8*)(lds + ((unsigned)(KB_OFF + (kq*2+k)*4096 + (mt*16+lr)*64 + lg*16) ^ swzR));
          acc[mt] = __builtin_amdgcn_mfma_f32_16x16x32_bf16(afr, bfrP[k], acc[mt], 0,0,0);
        }
      }
    }
    #pragma unroll
    for(int mt=0; mt<4; ++mt){
      #pragma unroll
      for(int i=0;i<4;++i){
        int r = mt*16 + lg*4 + i;
        if(r<49){
          int ii=r/7, jj=r-ii*7;
          float val = acc[mt][i] + pbP + xwin[(size_t)c*3136 + ii*56 + jj];
          *(u16*)(lds + ((((unsigned)r)*512u + ((unsigned)c)*2u) ^ (((unsigned)(r&7))<<4))) = f2b(val);
        }
      }
    }
  }
  __syncthreads();

  // ---- writeout: xt linear bf16 [49][256], fully coalesced ----
  for(int u=tid; u<12544; u+=1024){
    int r = u>>8, c = u&255;
    xtbuf[(size_t)win*12544 + u] = *(const u16*)(lds + ((((unsigned)r)*512u + ((unsigned)c)*2u) ^ (((unsigned)(r&7))<<4)));
  }
}

// ---------------- k_mlp: LN2 + MLP + residual -> x2lin ----------------
// LDS 96K: h2s swz bf16[64][256] at [0,32K); hid0 [32K,64K); hid1 [64K,96K)
#define MLP_LDS 98304

__global__ __launch_bounds__(1024,4) void k_mlp(
    const u16* __restrict__ xtbuf,
    const u16* __restrict__ w1, const float* __restrict__ b1v,
    const u16* __restrict__ w2, const float* __restrict__ b2v,
    const float* __restrict__ g2, const float* __restrict__ bt2,
    u16* __restrict__ x2lin)
{
  extern __shared__ char lds[];
  const int tid = threadIdx.x;
  const int wv = tid >> 6, l = tid & 63;
  const int lr = l & 15, lg = l >> 4;
  const unsigned swzA = ((unsigned)(lr & 7)) << 4;
  const int win = ((blockIdx.x & 7) << 8) | (blockIdx.x >> 3);
  const size_t base = (size_t)win*12544;

  // ---- LN2 from global xt (coalesced) -> h2s swz; zero pads ----
  {
    float gg[4], bb2[4];
    #pragma unroll
    for(int k2=0;k2<4;++k2){ gg[k2]=g2[l+64*k2]; bb2[k2]=bt2[l+64*k2]; }
    #pragma unroll
    for(int rr=0; rr<4; ++rr){
      int r = wv*4 + rr;
      if(r<49){
        float v[4];
        #pragma unroll
        for(int k2=0;k2<4;++k2) v[k2] = b2f(xtbuf[base + r*256 + l + 64*k2]);
        float sm=v[0]+v[1]+v[2]+v[3];
        float sq=v[0]*v[0]+v[1]*v[1]+v[2]*v[2]+v[3]*v[3];
        #pragma unroll
        for(int off=32;off>=1;off>>=1){ sm+=__shfl_xor(sm,off); sq+=__shfl_xor(sq,off); }
        float mu=sm*(1.f/256.f), var=sq*(1.f/256.f)-mu*mu, rs=rsqrtf(var+1e-5f);
        #pragma unroll
        for(int k2=0;k2<4;++k2){
          int c=l+64*k2;
          unsigned off2 = (((unsigned)r)*512u + ((unsigned)c)*2u) ^ (((unsigned)(r&7))<<4);
          *(u16*)(lds + off2) = f2b((v[k2]-mu)*rs*gg[k2]+bb2[k2]);
        }
      }
    }
  }
  for(int m=tid; m<3840; m+=1024){
    int r = 49 + (m>>8), c = m & 255;
    *(u16*)(lds + ((((unsigned)r)*512u + ((unsigned)c)*2u) ^ (((unsigned)(r&7))<<4))) = 0;
  }
  __syncthreads();

  // ---- MLP with double-buffered hid; quarter fragments, acc[4] ILP ----
  const int hcol = wv*16 + lr;
  f32x4 acc2[4];
  #pragma unroll
  for(int mt=0;mt<4;++mt) acc2[mt]=(f32x4){0.f,0.f,0.f,0.f};

  // G1(0) -> hid0 (32768)
  {
    const u16* wrow = w1 + (size_t)hcol*256 + lg*8;
    const float bias1 = b1v[hcol];
    f32x4 acc[4];
    #pragma unroll
    for(int mt=0;mt<4;++mt) acc[mt]=(f32x4){0.f,0.f,0.f,0.f};
    #pragma unroll
    for(int kq=0; kq<4; ++kq){
      bf16x8 bfr1[2];
      #pragma unroll
      for(int k=0;k<2;++k) bfr1[k] = *(const bf16x8*)(wrow + kq*64 + k*32);
      #pragma unroll
      for(int mt=0; mt<4; ++mt){
        #pragma unroll
        for(int k=0;k<2;++k){
          bf16x8 afr = *(const bf16x8*)(lds + ((((unsigned)(mt*16+lr))*512u + (unsigned)((kq*2+k)*64+lg*16)) ^ swzA));
          acc[mt] = __builtin_amdgcn_mfma_f32_16x16x32_bf16(afr, bfr1[k], acc[mt], 0,0,0);
        }
      }
    }
    #pragma unroll
    for(int mt=0; mt<4; ++mt)
      #pragma unroll
      for(int i2=0;i2<4;++i2){
        int r = mt*16 + lg*4 + i2;
        *(u16*)(lds + 32768u + ((((unsigned)r)*512u + ((unsigned)hcol)*2u) ^ (((unsigned)(r&7))<<4))) = f2b(gelu(acc[mt][i2]+bias1));
      }
  }
  __syncthreads();

  for(int kc=0; kc<4; ++kc){
    // G1(kc+1) -> other hid buffer
    if(kc<3){
      const int gcol = (kc+1)*256 + hcol;
      const u16* wrow = w1 + (size_t)gcol*256 + lg*8;
      const float biasN = b1v[gcol];
      const unsigned dst = ((kc+1)&1) ? 65536u : 32768u;
      f32x4 acc[4];
      #pragma unroll
      for(int mt=0;mt<4;++mt) acc[mt]=(f32x4){0.f,0.f,0.f,0.f};
      #pragma unroll
      for(int kq=0; kq<4; ++kq){
        bf16x8 bfrN[2];
        #pragma unroll
        for(int k=0;k<2;++k) bfrN[k] = *(const bf16x8*)(wrow + kq*64 + k*32);
        #pragma unroll
        for(int mt=0; mt<4; ++mt){
          #pragma unroll
          for(int k=0;k<2;++k){
            bf16x8 afr = *(const bf16x8*)(lds + ((((unsigned)(mt*16+lr))*512u + (unsigned)((kq*2+k)*64+lg*16)) ^ swzA));
            acc[mt] = __builtin_amdgcn_mfma_f32_16x16x32_bf16(afr, bfrN[k], acc[mt], 0,0,0);
          }
        }
      }
      #pragma unroll
      for(int mt=0; mt<4; ++mt)
        #pragma unroll
        for(int i2=0;i2<4;++i2){
          int r = mt*16 + lg*4 + i2;
          *(u16*)(lds + dst + ((((unsigned)r)*512u + ((unsigned)hcol)*2u) ^ (((unsigned)(r&7))<<4))) = f2b(gelu(acc[mt][i2]+biasN));
        }
    }
    // G2(kc) reads current hid buffer
    {
      const u16* wrow = w2 + (size_t)hcol*1024 + kc*256 + lg*8;
      const unsigned src = (kc&1) ? 65536u : 32768u;
      __builtin_amdgcn_s_setprio(1);
      #pragma unroll
      for(int kq=0; kq<4; ++kq){
        bf16x8 bfr2[2];
        #pragma unroll
        for(int k=0;k<2;++k) bfr2[k] = *(const bf16x8*)(wrow + kq*64 + k*32);
        #pragma unroll
        for(int mt=0; mt<4; ++mt){
          #pragma unroll
          for(int k=0;k<2;++k){
            bf16x8 afr = *(const bf16x8*)(lds + src + ((((unsigned)(mt*16+lr))*512u + (unsigned)((kq*2+k)*64+lg*16)) ^ swzA));
            acc2[mt] = __builtin_amdgcn_mfma_f32_16x16x32_bf16(afr, bfr2[k], acc2[mt], 0,0,0);
          }
        }
      }
      __builtin_amdgcn_s_setprio(0);
    }
    __syncthreads();
  }

  // ---- epilogue: final = mlp + b2 + xt(residual, global L2-hot) -> LDS linear ----
  u16* fin = (u16*)(lds + 32768);      // hid buffers dead
  {
    const int c = hcol;
    const float biasc = b2v[c];
    #pragma unroll
    for(int mt=0; mt<4; ++mt){
      #pragma unroll
      for(int i2=0;i2<4;++i2){
        int r = mt*16 + lg*4 + i2;
        if(r<49){
          float resid = b2f(xtbuf[base + r*256 + c]);
          fin[r*256 + c] = f2b(acc2[mt][i2] + biasc + resid);
        }
      }
    }
  }
  __syncthreads();

  // ---- writeout: x2lin linear, fully coalesced ----
  for(int u=tid; u<12544; u+=1024)
    x2lin[base + u] = fin[u];
}

extern "C" void kernel_launch(void* const* d_in, const int* in_sizes, int n_in,
                              void* d_out, int out_size, void* d_ws, size_t ws_size,
                              hipStream_t stream) {
  const float* x      = (const float*)d_in[0];
  const float* qkv_w  = (const float*)d_in[1];
  const float* qkv_b  = (const float*)d_in[2];
  const float* proj_w = (const float*)d_in[3];
  const float* proj_b = (const float*)d_in[4];
  const float* btab   = (const float*)d_in[5];
  const float* ln1g   = (const float*)d_in[6];
  const float* ln1b   = (const float*)d_in[7];
  const float* ln2g   = (const float*)d_in[8];
  const float* ln2b   = (const float*)d_in[9];
  const float* w1     = (const float*)d_in[10];
  const float* b1     = (const float*)d_in[11];
  const float* w2     = (const float*)d_in[12];
  const float* b2     = (const float*)d_in[13];

  char* ws = (char*)d_ws;
  float* biasT = (float*)ws;                     // 131,072 B
  u16*   wq    = (u16*)(ws + 131072);            // 393,216 B
  u16*   wp    = (u16*)(ws + 524288);            // 131,072 B
  u16*   w1b   = (u16*)(ws + 655360);            // 524,288 B
  u16*   w2b   = (u16*)(ws + 1179648);           // 524,288 B
  u16*   x2l   = (u16*)(ws + 1703936);           // 51,380,224 B -> total 53,084,160 B
  u16*   xtb   = (u16*)d_out;                    // xt scratch; k_post overwrites d_out after

  k_prep<<<3200, TB, 0, stream>>>(qkv_w, proj_w, w1, w2, btab, wq, wp, w1b, w2b, biasT);

  hipFuncSetAttribute((const void*)k_attn, hipFuncAttributeMaxDynamicSharedMemorySize, ATT_LDS);
  hipFuncSetAttribute((const void*)k_mlp,  hipFuncAttributeMaxDynamicSharedMemorySize, MLP_LDS);
  k_attn<<<2048, 1024, ATT_LDS, stream>>>(x, wq, qkv_b, wp, proj_b, biasT, ln1g, ln1b, xtb);
  k_mlp <<<2048, 1024, MLP_LDS, stream>>>(xtb, w1b, b1, w2b, b2, ln2g, ln2b, x2l);
  k_post<<<2048, 256, 0, stream>>>(x2l, (float*)d_out);
}

// Round 19
// 704.397 us; speedup vs baseline: 1.0582x; 1.0145x over previous
//
#include <hip/hip_runtime.h>
#include <math.h>

#define TB 256

typedef short bf16x8 __attribute__((ext_vector_type(8)));
typedef short s16x4 __attribute__((ext_vector_type(4)));
typedef float f32x4 __attribute__((ext_vector_type(4)));
typedef unsigned short u16;

__device__ __forceinline__ float b2f(u16 u){
  union{unsigned i; float f;} v; v.i=((unsigned)u)<<16; return v.f;
}
__device__ __forceinline__ u16 f2b(float f){
  union{float ff; unsigned i;} v; v.ff=f;
  return (u16)((v.i + 0x7FFFu + ((v.i>>16)&1u))>>16);
}

// exact-GELU via Abramowitz-Stegun 7.1.26 erf (|err|<1.5e-7), no libcall
__device__ __forceinline__ float gelu(float x){
  float z = fabsf(x)*0.70710678118654752f;
  float t = 1.0f/fmaf(0.3275911f, z, 1.0f);
  float p = t*fmaf(t, fmaf(t, fmaf(t, fmaf(t, 1.061405429f, -1.453152027f), 1.421413741f), -0.284496736f), 0.254829592f);
  float erfz = fmaf(-p, __expf(-z*z), 1.0f);
  float s = (x >= 0.f) ? erfz : -erfz;
  return 0.5f*x*(1.0f + s);
}

// ---------------- fused prep: weight bf16 conversion + biasT [h][k][q] 64x64 ----------------
__global__ void k_prep(const float* __restrict__ qkv_w, const float* __restrict__ proj_w,
                       const float* __restrict__ w1, const float* __restrict__ w2,
                       const float* __restrict__ btab,
                       u16* __restrict__ wq, u16* __restrict__ wp,
                       u16* __restrict__ w1b, u16* __restrict__ w2b,
                       float* __restrict__ biasT){
  int i = blockIdx.x*TB + threadIdx.x;
  if(i < 196608){ wq[i] = f2b(qkv_w[i]); return; }
  i -= 196608;
  if(i < 65536){ wp[i] = f2b(proj_w[i]); return; }
  i -= 65536;
  if(i < 262144){ w1b[i] = f2b(w1[i]); return; }
  i -= 262144;
  if(i < 262144){ w2b[i] = f2b(w2[i]); return; }
  i -= 262144;
  if(i < 32768){
    int h = i>>12, kq = i&4095, k = kq>>6, q = kq&63;
    float v = 0.f;
    if(k<49 && q<49){
      int qi=q/7, qj=q-qi*7, ki=k/7, kj=k-ki*7;
      v = btab[((qi-ki+6)*13 + (qj-kj+6))*8 + h];
    }
    biasT[i] = v;
  }
}

// ---------------- window-reverse transpose: x2lin bf16[2048][49][256] -> out f32[B,C,H,W] ----------------
__global__ __launch_bounds__(256) void k_post(const u16* __restrict__ x2lin, float* __restrict__ out){
  __shared__ u16 tile[12544];            // [cc 32][ww 8][r 49]
  const int bid = blockIdx.x;
  const int bb = bid>>6, wh=(bid>>3)&7, chunk=bid&7;
  const int wb = bb*64 + wh*8;
  for(int e=threadIdx.x; e<12544; e+=256){
    int ww = e/1568, rem = e - ww*1568, r = rem>>5, cc = rem&31;
    tile[cc*392 + ww*49 + r] = x2lin[(size_t)(wb+ww)*12544 + r*256 + chunk*32 + cc];
  }
  __syncthreads();
  for(int idx=threadIdx.x; idx<12544; idx+=256){
    int c = idx/392, rem = idx - c*392, ii = rem/56, w = rem - ii*56;
    int ww = w/7, j = w - ww*7;
    out[((size_t)(bb*256 + chunk*32 + c))*3136 + (size_t)(wh*7+ii)*56 + w]
        = b2f(tile[c*392 + ww*49 + ii*7 + j]);
  }
}

// ---------------- k_attn: LN1 + QKV + attention + proj + residual -> xt linear ----------------
#define QB_OFF  32768
#define KB_OFF  65536
#define VT_OFF  98304
#define XS_OFF  65536
#define ATT_LDS 131072

__global__ __launch_bounds__(1024,4) void k_attn(
    const float* __restrict__ x,
    const u16* __restrict__ wqkv,  const float* __restrict__ bqkv,
    const u16* __restrict__ wproj, const float* __restrict__ bproj,
    const float* __restrict__ biasT,
    const float* __restrict__ g1, const float* __restrict__ bt1,
    u16* __restrict__ xtbuf)          // xt bf16 [win][49][256] (scratch in d_out)
{
  extern __shared__ char lds[];
  const int tid = threadIdx.x;
  const int wv = tid >> 6, l = tid & 63;
  const int lr = l & 15, lg = l >> 4;
  const unsigned swzA = ((unsigned)(lr & 7)) << 4;
  const unsigned swzR = ((unsigned)((lr>>2) & 3)) << 4;
  const int win = ((blockIdx.x & 7) << 8) | (blockIdx.x >> 3);
  const int bb = win >> 6, wh = (win >> 3) & 7, ww = win & 7;
  const float* xwin = x + (size_t)bb*802816 + (size_t)wh*392 + ww*7;

  // ---- phase 0a: coalesced stage of x window -> xs f32[256][53] ----
  float* xs = (float*)(lds + XS_OFF);
  {
    const int j = tid & 7, rbase = tid >> 3;
    #pragma unroll
    for(int it=0; it<14; ++it){
      int run = it*128 + rbase;
      int c = run/7, ii = run - (run/7)*7;
      if(j<7) xs[c*53 + ii*7 + j] = xwin[(size_t)c*3136 + ii*56 + j];
    }
  }
  __syncthreads();

  // ---- phase 0b: LN1 from xs -> h_s bf16 swz; zero h_s pad rows ----
  {
    float gg[4], bgm[4];
    #pragma unroll
    for(int k2=0;k2<4;++k2){ gg[k2]=g1[l+64*k2]; bgm[k2]=bt1[l+64*k2]; }
    #pragma unroll
    for(int s=0;s<4;++s){
      int n = wv + s*16;
      if(n<49){
        float xv[4];
        #pragma unroll
        for(int k2=0;k2<4;++k2) xv[k2] = xs[(l+64*k2)*53 + n];
        float sm=0.f, sq=0.f;
        #pragma unroll
        for(int k2=0;k2<4;++k2){ sm+=xv[k2]; sq+=xv[k2]*xv[k2]; }
        #pragma unroll
        for(int off=32;off>=1;off>>=1){ sm+=__shfl_xor(sm,off); sq+=__shfl_xor(sq,off); }
        float mu=sm*(1.f/256.f), var=sq*(1.f/256.f)-mu*mu;
        float rs=rsqrtf(var+1e-5f);
        #pragma unroll
        for(int k2=0;k2<4;++k2){
          int c=l+64*k2;
          unsigned off2 = (((unsigned)n)*512u + ((unsigned)c)*2u) ^ (((unsigned)(n&7))<<4);
          *(u16*)(lds + off2) = f2b((xv[k2]-mu)*rs*gg[k2]+bgm[k2]);
        }
      }
    }
  }
  for(int m=tid; m<3840; m+=1024) *(u16*)(lds + 49*512 + m*2) = 0;
  __syncthreads();          // xs dead

  // ---- Vt pad zeroing (r>=49 only), disjoint from phase-1 writes ----
  for(int m=tid; m<3840; m+=1024){
    int hd = m/480, rm = m - hd*480;
    int d = rm/15, r = 49 + (rm - (rm/15)*15);
    *(u16*)(lds + ((unsigned)(VT_OFF + hd*4096 + d*128 + r*2) ^ ((((unsigned)d)&7u)<<4))) = 0;
  }

  // ---- phase 1: QKV GEMM (transposed D[c][r]); quarter fragment loads, acc[4] ILP ----
  for(int ct=wv; ct<48; ct+=16){
    const u16* wrow = wqkv + ((size_t)(ct*16+lr))*256 + lg*8;
    f32x4 acc[4];
    #pragma unroll
    for(int rt=0;rt<4;++rt) acc[rt]=(f32x4){0.f,0.f,0.f,0.f};
    #pragma unroll
    for(int kq=0; kq<4; ++kq){
      bf16x8 bfr[2];
      #pragma unroll
      for(int k=0;k<2;++k) bfr[k] = *(const bf16x8*)(wrow + kq*64 + k*32);
      #pragma unroll
      for(int rt=0; rt<4; ++rt){
        #pragma unroll
        for(int k=0;k<2;++k){
          bf16x8 afr = *(const bf16x8*)(lds + ((((unsigned)(rt*16+lr))*512u + (unsigned)((kq*2+k)*64+lg*16)) ^ swzA));
          acc[rt] = __builtin_amdgcn_mfma_f32_16x16x32_bf16(bfr[k], afr, acc[rt], 0,0,0);
        }
      }
    }
    f32x4 b4 = *(const f32x4*)(bqkv + ct*16 + lg*4);
    const int s3 = ct>>4, hd = (ct>>1)&7, db = (ct&1)*16 + lg*4;
    #pragma unroll
    for(int rt=0; rt<4; ++rt){
      const int r = rt*16 + lr;
      if(r<49){
        if(s3==0){
          s16x4 pk;
          #pragma unroll
          for(int i=0;i<4;++i) pk[i] = (short)f2b((acc[rt][i]+b4[i])*0.35355339059327373f);
          *(s16x4*)(lds + ((unsigned)(QB_OFF + hd*4096 + r*64 + db*2) ^ swzR)) = pk;
        } else if(s3==1){
          s16x4 pk;
          #pragma unroll
          for(int i=0;i<4;++i) pk[i] = (short)f2b(acc[rt][i]+b4[i]);
          *(s16x4*)(lds + ((unsigned)(KB_OFF + hd*4096 + r*64 + db*2) ^ swzR)) = pk;
        } else {
          #pragma unroll
          for(int i=0;i<4;++i)
            *(u16*)(lds + ((unsigned)(VT_OFF + hd*4096 + (db+i)*128 + r*2) ^ ((((unsigned)(db+i))&7u)<<4))) = f2b(acc[rt][i]+b4[i]);
        }
      }
    }
  }
  __syncthreads();

  // ---- phase 2: attention; 2 waves per head, qt halves sequential ----
  {
    const int h = wv & 7, half = wv >> 3;
    s16x4 pkk[2][4];
    #pragma unroll
    for(int j=0;j<2;++j){
      const int qt = half*2 + j;
      bf16x8 qf = *(const bf16x8*)(lds + ((unsigned)(QB_OFF + h*4096 + (qt*16+lr)*64 + lg*16) ^ swzR));
      f32x4 st[4];
      #pragma unroll
      for(int kt=0;kt<4;++kt){
        bf16x8 kfk = *(const bf16x8*)(lds + ((unsigned)(KB_OFF + h*4096 + (kt*16+lr)*64 + lg*16) ^ swzR));
        f32x4 bini;
        #pragma unroll
        for(int i=0;i<4;++i) bini[i] = biasT[h*4096 + (kt*16+lg*4+i)*64 + qt*16+lr];
        st[kt] = __builtin_amdgcn_mfma_f32_16x16x32_bf16(kfk, qf, bini, 0,0,0);
      }
      #pragma unroll
      for(int i=0;i<4;++i)
        if(!(lg==0 && i==0)) st[3][i] = -1e30f;   // only k=48 valid in kt=3

      float mx = -1e30f;
      #pragma unroll
      for(int kt=0;kt<4;++kt)
        #pragma unroll
        for(int i=0;i<4;++i) mx = fmaxf(mx, st[kt][i]);
      mx = fmaxf(mx, __shfl_xor(mx,16));
      mx = fmaxf(mx, __shfl_xor(mx,32));
      float su = 0.f;
      #pragma unroll
      for(int kt=0;kt<4;++kt)
        #pragma unroll
        for(int i=0;i<4;++i){ float p = __expf(st[kt][i]-mx); st[kt][i]=p; su+=p; }
      su += __shfl_xor(su,16);
      su += __shfl_xor(su,32);
      float inv = 1.f/su;
      #pragma unroll
      for(int kt=0;kt<4;++kt)
        #pragma unroll
        for(int i=0;i<4;++i) pkk[j][kt][i] = (short)f2b(st[kt][i]*inv);
    }
    __syncthreads();       // Qbuf/Kbuf reads done -> P may overwrite [0,64K)

    char* Pb = lds + h*8192;
    #pragma unroll
    for(int j=0;j<2;++j){
      const unsigned rq = (unsigned)((half*2+j)*16 + lr);
      #pragma unroll
      for(int kt=0;kt<4;++kt)
        *(s16x4*)(Pb + ((rq*128u + (unsigned)(kt*32+lg*8)) ^ swzA)) = pkk[j][kt];
    }
    #pragma unroll
    for(int j=0;j<2;++j){
      const int qt = half*2 + j;
      const unsigned rq = (unsigned)(qt*16 + lr);
      bf16x8 pf0 = *(const bf16x8*)(Pb + ((rq*128u + (unsigned)(lg*16)) ^ swzA));
      bf16x8 pf1 = *(const bf16x8*)(Pb + ((rq*128u + (unsigned)(64+lg*16)) ^ swzA));
      #pragma unroll
      for(int dt=0;dt<2;++dt){
        bf16x8 vf0 = *(const bf16x8*)(lds + ((unsigned)(VT_OFF + h*4096 + (dt*16+lr)*128 + lg*16) ^ swzA));
        bf16x8 vf1 = *(const bf16x8*)(lds + ((unsigned)(VT_OFF + h*4096 + (dt*16+lr)*128 + 64+lg*16) ^ swzA));
        f32x4 o = {0.f,0.f,0.f,0.f};
        o = __builtin_amdgcn_mfma_f32_16x16x32_bf16(pf0, vf0, o, 0,0,0);
        o = __builtin_amdgcn_mfma_f32_16x16x32_bf16(pf1, vf1, o, 0,0,0);
        #pragma unroll
        for(int i=0;i<4;++i)
          *(u16*)(lds + ((unsigned)(KB_OFF + h*4096 + (qt*16+lg*4+i)*64 + (dt*16+lr)*2) ^ (((unsigned)lg)<<4))) = f2b(o[i]);
      }
    }
  }
  __syncthreads();         // O ready; P dead

  // ---- phase 3: proj GEMM + residual -> xt bf16 swz at [0,32K) ----
  {
    const int c = wv*16 + lr;
    const u16* wrow = wproj + (size_t)c*256 + lg*8;
    const float pbP = bproj[c];
    f32x4 acc[4];
    #pragma unroll
    for(int mt=0;mt<4;++mt) acc[mt]=(f32x4){0.f,0.f,0.f,0.f};
    #pragma unroll
    for(int kq=0; kq<4; ++kq){
      bf16x8 bfrP[2];
      #pragma unroll
      for(int k=0;k<2;++k) bfrP[k] = *(const bf16x8*)(wrow + kq*64 + k*32);
      #pragma unroll
      for(int mt=0; mt<4; ++mt){
        #pragma unroll
        for(int k=0;k<2;++k){
          bf16x8 afr = *(const bf16x8*)(lds + ((unsigned)(KB_OFF + (kq*2+k)*4096 + (mt*16+lr)*64 + lg*16) ^ swzR));
          acc[mt] = __builtin_amdgcn_mfma_f32_16x16x32_bf16(afr, bfrP[k], acc[mt], 0,0,0);
        }
      }
    }
    #pragma unroll
    for(int mt=0; mt<4; ++mt){
      #pragma unroll
      for(int i=0;i<4;++i){
        int r = mt*16 + lg*4 + i;
        if(r<49){
          int ii=r/7, jj=r-ii*7;
          float val = acc[mt][i] + pbP + xwin[(size_t)c*3136 + ii*56 + jj];
          *(u16*)(lds + ((((unsigned)r)*512u + ((unsigned)c)*2u) ^ (((unsigned)(r&7))<<4))) = f2b(val);
        }
      }
    }
  }
  __syncthreads();

  // ---- writeout: xt linear bf16 [49][256], fully coalesced ----
  for(int u=tid; u<12544; u+=1024){
    int r = u>>8, c = u&255;
    xtbuf[(size_t)win*12544 + u] = *(const u16*)(lds + ((((unsigned)r)*512u + ((unsigned)c)*2u) ^ (((unsigned)(r&7))<<4)));
  }
}

// ---------------- k_mlp: LN2 + MLP + residual -> x2lin; 512 thr, 256-VGPR budget ----------------
// LDS 96K: h2s swz bf16[64][256] at [0,32K); hid0 [32K,64K); hid1 [64K,96K)
#define MLP_LDS 98304

__global__ __launch_bounds__(512,2) void k_mlp(
    const u16* __restrict__ xtbuf,
    const u16* __restrict__ w1, const float* __restrict__ b1v,
    const u16* __restrict__ w2, const float* __restrict__ b2v,
    const float* __restrict__ g2, const float* __restrict__ bt2,
    u16* __restrict__ x2lin)
{
  extern __shared__ char lds[];
  const int tid = threadIdx.x;
  const int wv = tid >> 6, l = tid & 63;        // wv in [0,8)
  const int lr = l & 15, lg = l >> 4;
  const unsigned swzA = ((unsigned)(lr & 7)) << 4;
  const int win = ((blockIdx.x & 7) << 8) | (blockIdx.x >> 3);
  const size_t base = (size_t)win*12544;

  // ---- LN2 from global xt (coalesced) -> h2s swz; zero pads ----
  {
    float gg[4], bb2[4];
    #pragma unroll
    for(int k2=0;k2<4;++k2){ gg[k2]=g2[l+64*k2]; bb2[k2]=bt2[l+64*k2]; }
    #pragma unroll
    for(int rr=0; rr<8; ++rr){
      int r = wv*8 + rr;
      if(r<49){
        float v[4];
        #pragma unroll
        for(int k2=0;k2<4;++k2) v[k2] = b2f(xtbuf[base + r*256 + l + 64*k2]);
        float sm=v[0]+v[1]+v[2]+v[3];
        float sq=v[0]*v[0]+v[1]*v[1]+v[2]*v[2]+v[3]*v[3];
        #pragma unroll
        for(int off=32;off>=1;off>>=1){ sm+=__shfl_xor(sm,off); sq+=__shfl_xor(sq,off); }
        float mu=sm*(1.f/256.f), var=sq*(1.f/256.f)-mu*mu, rs=rsqrtf(var+1e-5f);
        #pragma unroll
        for(int k2=0;k2<4;++k2){
          int c=l+64*k2;
          unsigned off2 = (((unsigned)r)*512u + ((unsigned)c)*2u) ^ (((unsigned)(r&7))<<4);
          *(u16*)(lds + off2) = f2b((v[k2]-mu)*rs*gg[k2]+bb2[k2]);
        }
      }
    }
  }
  for(int m=tid; m<3840; m+=512){
    int r = 49 + (m>>8), c = m & 255;
    *(u16*)(lds + ((((unsigned)r)*512u + ((unsigned)c)*2u) ^ (((unsigned)(r&7))<<4))) = 0;
  }
  __syncthreads();

  // ---- MLP, 2 column tiles per wave; double-buffered hid ----
  f32x4 acc2[2][4];
  #pragma unroll
  for(int nt=0;nt<2;++nt)
    #pragma unroll
    for(int mt=0;mt<4;++mt) acc2[nt][mt]=(f32x4){0.f,0.f,0.f,0.f};

  // G1(0) -> hid0 (32768)
  #pragma unroll
  for(int nt=0; nt<2; ++nt){
    const int hcol = wv*32 + nt*16 + lr;
    const u16* wrow = w1 + (size_t)hcol*256 + lg*8;
    const float bias1 = b1v[hcol];
    f32x4 acc[4];
    #pragma unroll
    for(int mt=0;mt<4;++mt) acc[mt]=(f32x4){0.f,0.f,0.f,0.f};
    #pragma unroll
    for(int kh=0; kh<2; ++kh){
      bf16x8 bfr1[4];
      #pragma unroll
      for(int k=0;k<4;++k) bfr1[k] = *(const bf16x8*)(wrow + kh*128 + k*32);
      #pragma unroll
      for(int mt=0; mt<4; ++mt){
        #pragma unroll
        for(int k=0;k<4;++k){
          bf16x8 afr = *(const bf16x8*)(lds + ((((unsigned)(mt*16+lr))*512u + (unsigned)((kh*4+k)*64+lg*16)) ^ swzA));
          acc[mt] = __builtin_amdgcn_mfma_f32_16x16x32_bf16(afr, bfr1[k], acc[mt], 0,0,0);
        }
      }
    }
    #pragma unroll
    for(int mt=0; mt<4; ++mt)
      #pragma unroll
      for(int i2=0;i2<4;++i2){
        int r = mt*16 + lg*4 + i2;
        *(u16*)(lds + 32768u + ((((unsigned)r)*512u + ((unsigned)hcol)*2u) ^ (((unsigned)(r&7))<<4))) = f2b(gelu(acc[mt][i2]+bias1));
      }
  }
  __syncthreads();

  for(int kc=0; kc<4; ++kc){
    // G1(kc+1) -> other hid buffer
    if(kc<3){
      const unsigned dst = ((kc+1)&1) ? 65536u : 32768u;
      #pragma unroll
      for(int nt=0; nt<2; ++nt){
        const int hcol = wv*32 + nt*16 + lr;
        const int gcol = (kc+1)*256 + hcol;
        const u16* wrow = w1 + (size_t)gcol*256 + lg*8;
        const float biasN = b1v[gcol];
        f32x4 acc[4];
        #pragma unroll
        for(int mt=0;mt<4;++mt) acc[mt]=(f32x4){0.f,0.f,0.f,0.f};
        #pragma unroll
        for(int kh=0; kh<2; ++kh){
          bf16x8 bfrN[4];
          #pragma unroll
          for(int k=0;k<4;++k) bfrN[k] = *(const bf16x8*)(wrow + kh*128 + k*32);
          #pragma unroll
          for(int mt=0; mt<4; ++mt){
            #pragma unroll
            for(int k=0;k<4;++k){
              bf16x8 afr = *(const bf16x8*)(lds + ((((unsigned)(mt*16+lr))*512u + (unsigned)((kh*4+k)*64+lg*16)) ^ swzA));
              acc[mt] = __builtin_amdgcn_mfma_f32_16x16x32_bf16(afr, bfrN[k], acc[mt], 0,0,0);
            }
          }
        }
        #pragma unroll
        for(int mt=0; mt<4; ++mt)
          #pragma unroll
          for(int i2=0;i2<4;++i2){
            int r = mt*16 + lg*4 + i2;
            *(u16*)(lds + dst + ((((unsigned)r)*512u + ((unsigned)hcol)*2u) ^ (((unsigned)(r&7))<<4))) = f2b(gelu(acc[mt][i2]+biasN));
          }
      }
    }
    // G2(kc) reads current hid buffer
    {
      const unsigned src = (kc&1) ? 65536u : 32768u;
      __builtin_amdgcn_s_setprio(1);
      #pragma unroll
      for(int nt=0; nt<2; ++nt){
        const int c = wv*32 + nt*16 + lr;
        const u16* wrow = w2 + (size_t)c*1024 + kc*256 + lg*8;
        #pragma unroll
        for(int kh=0; kh<2; ++kh){
          bf16x8 bfr2[4];
          #pragma unroll
          for(int k=0;k<4;++k) bfr2[k] = *(const bf16x8*)(wrow + kh*128 + k*32);
          #pragma unroll
          for(int mt=0; mt<4; ++mt){
            #pragma unroll
            for(int k=0;k<4;++k){
              bf16x8 afr = *(const bf16x8*)(lds + src + ((((unsigned)(mt*16+lr))*512u + (unsigned)((kh*4+k)*64+lg*16)) ^ swzA));
              acc2[nt][mt] = __builtin_amdgcn_mfma_f32_16x16x32_bf16(afr, bfr2[k], acc2[nt][mt], 0,0,0);
            }
          }
        }
      }
      __builtin_amdgcn_s_setprio(0);
    }
    __syncthreads();
  }

  // ---- epilogue: final = mlp + b2 + xt(residual, global L2-hot) -> LDS linear ----
  u16* fin = (u16*)(lds + 32768);      // hid buffers dead
  #pragma unroll
  for(int nt=0; nt<2; ++nt){
    const int c = wv*32 + nt*16 + lr;
    const float biasc = b2v[c];
    #pragma unroll
    for(int mt=0; mt<4; ++mt){
      #pragma unroll
      for(int i2=0;i2<4;++i2){
        int r = mt*16 + lg*4 + i2;
        if(r<49){
          float resid = b2f(xtbuf[base + r*256 + c]);
          fin[r*256 + c] = f2b(acc2[nt][mt][i2] + biasc + resid);
        }
      }
    }
  }
  __syncthreads();

  // ---- writeout: x2lin linear, fully coalesced ----
  for(int u=tid; u<12544; u+=512)
    x2lin[base + u] = fin[u];
}

extern "C" void kernel_launch(void* const* d_in, const int* in_sizes, int n_in,
                              void* d_out, int out_size, void* d_ws, size_t ws_size,
                              hipStream_t stream) {
  const float* x      = (const float*)d_in[0];
  const float* qkv_w  = (const float*)d_in[1];
  const float* qkv_b  = (const float*)d_in[2];
  const float* proj_w = (const float*)d_in[3];
  const float* proj_b = (const float*)d_in[4];
  const float* btab   = (const float*)d_in[5];
  const float* ln1g   = (const float*)d_in[6];
  const float* ln1b   = (const float*)d_in[7];
  const float* ln2g   = (const float*)d_in[8];
  const float* ln2b   = (const float*)d_in[9];
  const float* w1     = (const float*)d_in[10];
  const float* b1     = (const float*)d_in[11];
  const float* w2     = (const float*)d_in[12];
  const float* b2     = (const float*)d_in[13];

  char* ws = (char*)d_ws;
  float* biasT = (float*)ws;                     // 131,072 B
  u16*   wq    = (u16*)(ws + 131072);            // 393,216 B
  u16*   wp    = (u16*)(ws + 524288);            // 131,072 B
  u16*   w1b   = (u16*)(ws + 655360);            // 524,288 B
  u16*   w2b   = (u16*)(ws + 1179648);           // 524,288 B
  u16*   x2l   = (u16*)(ws + 1703936);           // 51,380,224 B -> total 53,084,160 B
  u16*   xtb   = (u16*)d_out;                    // xt scratch; k_post overwrites d_out after

  k_prep<<<3200, TB, 0, stream>>>(qkv_w, proj_w, w1, w2, btab, wq, wp, w1b, w2b, biasT);

  hipFuncSetAttribute((const void*)k_attn, hipFuncAttributeMaxDynamicSharedMemorySize, ATT_LDS);
  hipFuncSetAttribute((const void*)k_mlp,  hipFuncAttributeMaxDynamicSharedMemorySize, MLP_LDS);
  k_attn<<<2048, 1024, ATT_LDS, stream>>>(x, wq, qkv_b, wp, proj_b, biasT, ln1g, ln1b, xtb);
  k_mlp <<<2048, 512, MLP_LDS, stream>>>(xtb, w1b, b1, w2b, b2, ln2g, ln2b, x2l);
  k_post<<<2048, 256, 0, stream>>>(x2l, (float*)d_out);
}